// Round 13
// baseline (134.360 us; speedup 1.0000x reference)
//
#include <hip/hip_runtime.h>
#include <hip/hip_bf16.h>

#define HH 512
#define WW 512
#define HWSZ (HH*WW)
#define NB 32
#define NLD 100000
#define NF 16
#define EPSV 1e-3f
#define TILE 16
#define GR (TILE+4)    // grid halo tile 20x20
#define HCELLS (GR*GR) // 400
#define YR (TILE+2)    // y1/proj tile 18x18
#define NGRP 21        // ceil(324/16) pixel-groups for MFMA
#define PSLOTS (NGRP*16)  // 336
#define PSTRB 10       // proj row stride in shorts (taps 0..8 + pad)

#define NTILE 1024     // 32x32 tiles of 16x16
#define CAPT 256       // halo-bucket capacity (λ=152.6, σ=12.4 -> 8.3σ)

typedef __attribute__((ext_vector_type(8))) short bf16x8;
typedef __attribute__((ext_vector_type(4))) float f32x4;

static __device__ __forceinline__ unsigned short f2bfu(float f) {
  __hip_bfloat16 h = __float2bfloat16(f);
  return __builtin_bit_cast(unsigned short, h);
}

// HW packed bf16 convert: lo16=cvt(a), hi16=cvt(b)
static __device__ __forceinline__ unsigned cvtpk(float a, float b) {
  unsigned r;
  asm("v_cvt_pk_bf16_f32 %0, %1, %2" : "=v"(r) : "v"(a), "v"(b));
  return r;
}

// ---- prep: build BOTH MFMA A-fragments once.
// w2A: A[m=tap][k=ch] (proj);  w1A: A[m=ch][k=tap] (conv1). Lane l holds
// m=l&15, k=(l>>4)*8+jj. ----
__global__ void prep_k(const float* __restrict__ w1g, const float* __restrict__ w2g,
                       uint4* __restrict__ w2A, uint4* __restrict__ w1A) {
  int l = threadIdx.x;  // 64
  bf16x8 a2, a1;
  #pragma unroll
  for (int jj = 0; jj < 8; ++jj) {
    int m = l & 15, k = (l >> 4)*8 + jj;
    float v2 = (m < 9 && k < NF) ? w2g[m*NF + k] : 0.f;   // w2[tap][ch]
    float v1 = (k < 9)           ? w1g[k*NF + m] : 0.f;   // w1[tap][ch] -> A[ch][tap]
    a2[jj] = (short)f2bfu(v2);
    a1[jj] = (short)f2bfu(v1);
  }
  w2A[l] = __builtin_bit_cast(uint4, a2);
  w1A[l] = __builtin_bit_cast(uint4, a1);
}

// ---- bin: halo-bucket per 16x16 tile. Index i with cell (h,w) joins every
// tile whose 20x20 halo contains it (1..4 tiles, avg 1.56). entry = i<<9|pos,
// pos = position in the tile's 20x20 halo. The SAME bucket serves scatter
// (all entries) and gather (interior-pos entries) in conv_k. ----
__global__ __launch_bounds__(256) void bin_k(const int* __restrict__ idx,
    unsigned* __restrict__ g_tcnt, unsigned* __restrict__ g_tbkt) {
  __shared__ unsigned ht[NTILE], bt[NTILE];
  const int lid = threadIdx.x;
  for (int q = lid; q < NTILE; q += 256) ht[q] = 0;
  __syncthreads();
  for (int i = blockIdx.x*256 + lid; i < NLD; i += 64*256) {
    int cell = idx[i];
    int h = cell >> 9, w = cell & 511;
    int thA = (h-2)>>4, thB = (h+2)>>4;   // th ∈ {thA, thB} (ceil((h-17)/16), floor((h+2)/16))
    int twA = (w-2)>>4, twB = (w+2)>>4;
    #pragma unroll
    for (int ah = 0; ah < 2; ++ah) {
      int th = ah ? thB : thA;
      if (th < 0 || th > 31 || (ah && thB == thA)) continue;
      #pragma unroll
      for (int aw = 0; aw < 2; ++aw) {
        int tw = aw ? twB : twA;
        if (tw < 0 || tw > 31 || (aw && twB == twA)) continue;
        atomicAdd(&ht[th*32 + tw], 1u);
      }
    }
  }
  __syncthreads();
  for (int q = lid; q < NTILE; q += 256) {
    bt[q] = ht[q] ? atomicAdd(&g_tcnt[q], ht[q]) : 0u;
    ht[q] = 0;
  }
  __syncthreads();
  for (int i = blockIdx.x*256 + lid; i < NLD; i += 64*256) {
    int cell = idx[i];
    int h = cell >> 9, w = cell & 511;
    int thA = (h-2)>>4, thB = (h+2)>>4;
    int twA = (w-2)>>4, twB = (w+2)>>4;
    #pragma unroll
    for (int ah = 0; ah < 2; ++ah) {
      int th = ah ? thB : thA;
      if (th < 0 || th > 31 || (ah && thB == thA)) continue;
      #pragma unroll
      for (int aw = 0; aw < 2; ++aw) {
        int tw = aw ? twB : twA;
        if (tw < 0 || tw > 31 || (aw && twB == twA)) continue;
        int t = th*32 + tw;
        unsigned pt = bt[t] + atomicAdd(&ht[t], 1u);
        unsigned pos = (unsigned)(h - th*16 + 2)*20u + (unsigned)(w - tw*16 + 2);
        if (pt < CAPT) g_tbkt[(size_t)t*CAPT + pt] = ((unsigned)i << 9) | pos;
      }
    }
  }
}

// ---- conv: scatter + conv1 + BN + conv2 + gather, all in one kernel.
// LDS-accumulate the 20x20 halo from bucket entries (no global grid array),
// then the proven R12 dual-MFMA machinery, then gather from the same bucket. ----
__global__ __launch_bounds__(256, 4) void conv_k(
    const float* __restrict__ b1g,
    const float* __restrict__ gammag, const float* __restrict__ betag,
    const float* __restrict__ mmg, const float* __restrict__ mvg,
    const uint4* __restrict__ w1Ag, const uint4* __restrict__ w2Ag,
    const float* __restrict__ b2g, const float* __restrict__ x,
    const unsigned* __restrict__ g_tcnt, const unsigned* __restrict__ g_tbkt,
    float* __restrict__ out)
{
  __shared__ float s_gridf[HCELLS];                     // fp32 scatter accumulator
  __shared__ unsigned short s_gridb[HCELLS];            // halo tile, bf16
  __shared__ __align__(8) unsigned short s_projb[PSLOTS*PSTRB];  // proj bf16 (6.7 KB)
  __shared__ float s_ytile[256];                        // final y tile
  __shared__ __align__(16) float s_b1[NF], s_bnA[NF], s_bnB[NF];
  // ~10.3 KB LDS

  const int lid = threadIdx.x;
  const int j = blockIdx.x;
  const int b = j & 31;                    // XCD-affine batch
  const int tile = j >> 5;
  const int ty0 = (tile >> 5) * TILE, tx0 = (tile & 31) * TILE;

  const int l = lid & 63;
  const int wid = lid >> 6;
  const bf16x8 w1frag = __builtin_bit_cast(bf16x8, w1Ag[l]);
  const bf16x8 w2frag = __builtin_bit_cast(bf16x8, w2Ag[l]);

  if (lid >= 192 && lid < 192+NF) {
    int c = lid - 192;
    float sc = gammag[c] * rsqrtf(mvg[c] + EPSV);
    s_bnA[c] = sc;
    s_bnB[c] = betag[c] - mmg[c]*sc;
    s_b1[c] = b1g[c];
  }

  // ---- fused scatter: zero halo, ds_add bucket entries, quantize to bf16 ----
  for (int q = lid; q < HCELLS; q += 256) s_gridf[q] = 0.f;
  __syncthreads();

  const unsigned nT = min(g_tcnt[tile], (unsigned)CAPT);
  const unsigned* tb = g_tbkt + (size_t)tile*CAPT;
  const float* xb = x + (size_t)b*NLD;
  for (unsigned k2 = lid; k2 < nT; k2 += 256) {
    unsigned e = tb[k2];
    atomicAdd(&s_gridf[e & 511], xb[e >> 9]);   // ds_add_f32; pos < 400
  }
  __syncthreads();

  for (int q = lid; q < HCELLS; q += 256)
    s_gridb[q] = (unsigned short)(cvtpk(s_gridf[q], 0.f) & 0xFFFFu);
  __syncthreads();

  // ---- A+P on matrix pipe (proven R12) ----
  {
    const int n_px = l & 15, kg = l >> 4;
    const int ce = kg * 4;                 // this lane's conv1-output channel group
    const float4 eb = *(const float4*)&s_b1[ce];
    const float4 ea = *(const float4*)&s_bnA[ce];
    const float4 eB = *(const float4*)&s_bnB[ce];
    const int srcA = (n_px + (kg & 1)*32) * 4;   // bpermute byte indices
    const int srcB = srcA + 16*4;

    for (int grp = wid; grp < NGRP; grp += 4) {
      int p = grp*16 + n_px;
      unsigned rr = ((unsigned)p * 3641u) >> 16;     // p/18
      unsigned cc = (unsigned)p - rr*18u;
      int yh = ty0 - 1 + (int)rr, yw = tx0 - 1 + (int)cc;
      bool val = ((unsigned)yh < HH) & ((unsigned)yw < WW);
      const unsigned short* gpb = &s_gridb[rr*GR + cc];

      // G-frag: B[k=tap][n=px]; kg0 holds taps 0..7, kg1 tap 8, kg2/3 zero
      uint4 gu = make_uint4(0u, 0u, 0u, 0u);
      if (kg == 0) {
        gu.x = (unsigned)gpb[0]      | ((unsigned)gpb[1]      << 16);
        gu.y = (unsigned)gpb[2]      | ((unsigned)gpb[GR]     << 16);
        gu.z = (unsigned)gpb[GR+1]   | ((unsigned)gpb[GR+2]   << 16);
        gu.w = (unsigned)gpb[2*GR]   | ((unsigned)gpb[2*GR+1] << 16);
      } else if (kg == 1) {
        gu.x = (unsigned)gpb[2*GR+2];
      }
      bf16x8 gfrag = __builtin_bit_cast(bf16x8, gu);

      // conv1: D[m=ch][n=px] -> lane holds px=n_px, ch ce..ce+3
      f32x4 d1 = {0.f, 0.f, 0.f, 0.f};
      d1 = __builtin_amdgcn_mfma_f32_16x16x32_bf16(w1frag, gfrag, d1, 0, 0, 0);

      // bias + relu + BN, then pack; OOB y1 -> 0 (conv2 pads conv1 OUTPUT)
      float y0 = fmaf(fmaxf(d1[0] + eb.x, 0.f), ea.x, eB.x);
      float y1 = fmaf(fmaxf(d1[1] + eb.y, 0.f), ea.y, eB.y);
      float y2 = fmaf(fmaxf(d1[2] + eb.z, 0.f), ea.z, eB.z);
      float y3 = fmaf(fmaxf(d1[3] + eb.w, 0.f), ea.w, eB.w);
      unsigned u0 = val ? cvtpk(y0, y1) : 0u;   // ch {ce,ce+1}
      unsigned u1 = val ? cvtpk(y2, y3) : 0u;   // ch {ce+2,ce+3}

      // regroup 4ch/lane -> 8ch/lane (proj B-frag) via wave-internal bpermute
      unsigned B0 = __builtin_amdgcn_ds_bpermute(srcA, (int)u0);
      unsigned B1 = __builtin_amdgcn_ds_bpermute(srcA, (int)u1);
      unsigned B2 = __builtin_amdgcn_ds_bpermute(srcB, (int)u0);
      unsigned B3 = __builtin_amdgcn_ds_bpermute(srcB, (int)u1);
      if (kg >= 2) { B0 = B1 = B2 = B3 = 0u; }
      bf16x8 bfrag = __builtin_bit_cast(bf16x8, make_uint4(B0, B1, B2, B3));

      // proj: D[m=tap][n=px]
      f32x4 d = {0.f, 0.f, 0.f, 0.f};
      d = __builtin_amdgcn_mfma_f32_16x16x32_bf16(w2frag, bfrag, d, 0, 0, 0);
      if (kg < 2) {
        unsigned q0 = cvtpk(d[0], d[1]), q1 = cvtpk(d[2], d[3]);
        *(uint2*)&s_projb[p*PSTRB + kg*4] = make_uint2(q0, q1);
      } else if (kg == 2) {
        s_projb[p*PSTRB + 8] = (unsigned short)(cvtpk(d[0], d[0]) & 0xFFFFu);  // tap 8
      }
    }
  }
  __syncthreads();

  // ---- phase B: out-tile = b2 + sum_t proj[t] at shifted pixel -> LDS ----
  {
    const int ty = lid >> 4, tx = lid & 15;
    float acc = b2g[0];
    #pragma unroll
    for (int kh = 0; kh < 3; ++kh)
      #pragma unroll
      for (int kw = 0; kw < 3; ++kw) {
        unsigned u = s_projb[((ty+kh)*YR + tx+kw)*PSTRB + kh*3+kw];
        acc += __uint_as_float(u << 16);
      }
    s_ytile[lid] = acc;
  }
  __syncthreads();

  // ---- fused gather epilogue: interior-pos entries of the SAME bucket ----
  for (unsigned k2 = lid; k2 < nT; k2 += 256) {
    unsigned e = tb[k2];
    unsigned pos = e & 511;
    unsigned py = (pos * 3277u) >> 16;   // pos/20
    unsigned px = pos - py*20u;
    if (py >= 2 && py < 18 && px >= 2 && px < 18) {
      unsigned i = e >> 9;
      out[(size_t)b*NLD + i] = xb[i] + s_ytile[(py-2)*16 + (px-2)];
    }
  }
}

extern "C" void kernel_launch(void* const* d_in, const int* in_sizes, int n_in,
                              void* d_out, int out_size, void* d_ws, size_t ws_size,
                              hipStream_t stream) {
  const float* x     = (const float*)d_in[0];
  const float* w1    = (const float*)d_in[1];
  const float* b1    = (const float*)d_in[2];
  const float* gamma = (const float*)d_in[3];
  const float* beta  = (const float*)d_in[4];
  const float* mmean = (const float*)d_in[5];
  const float* mvar  = (const float*)d_in[6];
  const float* w2    = (const float*)d_in[7];
  const float* b2    = (const float*)d_in[8];
  const int*   idx   = (const int*)d_in[9];
  float* out = (float*)d_out;

  unsigned* g_tcnt = (unsigned*)d_ws;                     // 1024
  unsigned* g_tbkt = g_tcnt + NTILE;                      // NTILE*CAPT*4 = 1 MB
  uint4*    w2A    = (uint4*)(g_tbkt + (size_t)NTILE*CAPT);
  uint4*    w1A    = w2A + 64;

  (void)hipMemsetAsync(g_tcnt, 0, NTILE*sizeof(unsigned), stream);

  prep_k<<<dim3(1), dim3(64), 0, stream>>>(w1, w2, w2A, w1A);

  bin_k<<<dim3(64), dim3(256), 0, stream>>>(idx, g_tcnt, g_tbkt);

  conv_k<<<dim3(NB * NTILE), dim3(256), 0, stream>>>(
      b1, gamma, beta, mmean, mvar, w1A, w2A, b2, x, g_tcnt, g_tbkt, out);
}

// Round 14
// 129.556 us; speedup vs baseline: 1.0371x; 1.0371x over previous
//
#include <hip/hip_runtime.h>
#include <hip/hip_bf16.h>

#define HH 512
#define WW 512
#define HWSZ (HH*WW)
#define NB 32
#define NLD 100000
#define NF 16
#define EPSV 1e-3f
#define TILE 16
#define GR (TILE+4)    // grid halo tile 20x20
#define HCELLS (GR*GR) // 400
#define YR (TILE+2)    // y1/proj tile 18x18
#define NGRP 21        // ceil(324/16) pixel-groups for MFMA
#define PSLOTS (NGRP*16)  // 336
#define PSTRB 10       // proj row stride in shorts (taps 0..8 + pad)
#define PBUF (PSLOTS*PSTRB)

#define NTILE 1024     // 32x32 tiles of 16x16
#define CAPT 256       // halo-bucket capacity (λ=152.6, σ=12.4 -> 8.3σ)

typedef __attribute__((ext_vector_type(8))) short bf16x8;
typedef __attribute__((ext_vector_type(4))) float f32x4;

static __device__ __forceinline__ unsigned short f2bfu(float f) {
  __hip_bfloat16 h = __float2bfloat16(f);
  return __builtin_bit_cast(unsigned short, h);
}

// HW packed bf16 convert: lo16=cvt(a), hi16=cvt(b)
static __device__ __forceinline__ unsigned cvtpk(float a, float b) {
  unsigned r;
  asm("v_cvt_pk_bf16_f32 %0, %1, %2" : "=v"(r) : "v"(a), "v"(b));
  return r;
}

// ---- bin: halo-bucket per 16x16 tile (R13-proven). Block 0 additionally
// builds the two MFMA A-fragments (merged prep). entry = i<<9 | halo-pos. ----
__global__ __launch_bounds__(256) void bin_k(const int* __restrict__ idx,
    const float* __restrict__ w1g, const float* __restrict__ w2g,
    uint4* __restrict__ w2A, uint4* __restrict__ w1A,
    unsigned* __restrict__ g_tcnt, unsigned* __restrict__ g_tbkt) {
  __shared__ unsigned ht[NTILE], bt[NTILE];
  const int lid = threadIdx.x;

  if (blockIdx.x == 0 && lid < 64) {       // merged prep_k
    bf16x8 a2, a1;
    #pragma unroll
    for (int jj = 0; jj < 8; ++jj) {
      int m = lid & 15, k = (lid >> 4)*8 + jj;
      float v2 = (m < 9 && k < NF) ? w2g[m*NF + k] : 0.f;   // A[m=tap][k=ch]
      float v1 = (k < 9)           ? w1g[k*NF + m] : 0.f;   // A[m=ch][k=tap]
      a2[jj] = (short)f2bfu(v2);
      a1[jj] = (short)f2bfu(v1);
    }
    w2A[lid] = __builtin_bit_cast(uint4, a2);
    w1A[lid] = __builtin_bit_cast(uint4, a1);
  }

  for (int q = lid; q < NTILE; q += 256) ht[q] = 0;
  __syncthreads();
  for (int i = blockIdx.x*256 + lid; i < NLD; i += 64*256) {
    int cell = idx[i];
    int h = cell >> 9, w = cell & 511;
    int thA = (h-2)>>4, thB = (h+2)>>4;
    int twA = (w-2)>>4, twB = (w+2)>>4;
    #pragma unroll
    for (int ah = 0; ah < 2; ++ah) {
      int th = ah ? thB : thA;
      if (th < 0 || th > 31 || (ah && thB == thA)) continue;
      #pragma unroll
      for (int aw = 0; aw < 2; ++aw) {
        int tw = aw ? twB : twA;
        if (tw < 0 || tw > 31 || (aw && twB == twA)) continue;
        atomicAdd(&ht[th*32 + tw], 1u);
      }
    }
  }
  __syncthreads();
  for (int q = lid; q < NTILE; q += 256) {
    bt[q] = ht[q] ? atomicAdd(&g_tcnt[q], ht[q]) : 0u;
    ht[q] = 0;
  }
  __syncthreads();
  for (int i = blockIdx.x*256 + lid; i < NLD; i += 64*256) {
    int cell = idx[i];
    int h = cell >> 9, w = cell & 511;
    int thA = (h-2)>>4, thB = (h+2)>>4;
    int twA = (w-2)>>4, twB = (w+2)>>4;
    #pragma unroll
    for (int ah = 0; ah < 2; ++ah) {
      int th = ah ? thB : thA;
      if (th < 0 || th > 31 || (ah && thB == thA)) continue;
      #pragma unroll
      for (int aw = 0; aw < 2; ++aw) {
        int tw = aw ? twB : twA;
        if (tw < 0 || tw > 31 || (aw && twB == twA)) continue;
        int t = th*32 + tw;
        unsigned pt = bt[t] + atomicAdd(&ht[t], 1u);
        unsigned pos = (unsigned)(h - th*16 + 2)*20u + (unsigned)(w - tw*16 + 2);
        if (pt < CAPT) g_tbkt[(size_t)t*CAPT + pt] = ((unsigned)i << 9) | pos;
      }
    }
  }
}

// ---- conv: one tile x TWO batches per block. Two independent MFMA chains
// per group (one per batch) give the scheduler ILP where R13 was
// latency-bound; bucket decode / addressing / barriers amortized 2x. ----
__global__ __launch_bounds__(256, 4) void conv_k(
    const float* __restrict__ b1g,
    const float* __restrict__ gammag, const float* __restrict__ betag,
    const float* __restrict__ mmg, const float* __restrict__ mvg,
    const uint4* __restrict__ w1Ag, const uint4* __restrict__ w2Ag,
    const float* __restrict__ b2g, const float* __restrict__ x,
    const unsigned* __restrict__ g_tcnt, const unsigned* __restrict__ g_tbkt,
    float* __restrict__ out)
{
  __shared__ float s_gridf[2*HCELLS];                   // fp32 scatter acc; [0..511] reused as ytile
  __shared__ unsigned short s_gridb[2*HCELLS];          // halo tiles, bf16
  __shared__ __align__(8) unsigned short s_projb[2*PBUF];  // proj bf16, 13.4 KB
  __shared__ __align__(16) float s_b1[NF], s_bnA[NF], s_bnB[NF];
  // ~18.4 KB -> 8 blocks/CU (if VGPR <= 64)

  const int lid = threadIdx.x;
  const int j = blockIdx.x;
  const int b0 = (j & 15) * 2;             // batch pair
  const int tile = j >> 4;
  const int ty0 = (tile >> 5) * TILE, tx0 = (tile & 31) * TILE;

  const int l = lid & 63;
  const int wid = lid >> 6;
  const bf16x8 w1frag = __builtin_bit_cast(bf16x8, w1Ag[l]);
  const bf16x8 w2frag = __builtin_bit_cast(bf16x8, w2Ag[l]);

  if (lid >= 192 && lid < 192+NF) {
    int c = lid - 192;
    float sc = gammag[c] * rsqrtf(mvg[c] + EPSV);
    s_bnA[c] = sc;
    s_bnB[c] = betag[c] - mmg[c]*sc;
    s_b1[c] = b1g[c];
  }

  // ---- fused scatter for both batches ----
  for (int q = lid; q < 2*HCELLS; q += 256) s_gridf[q] = 0.f;
  __syncthreads();

  const unsigned nT = min(g_tcnt[tile], (unsigned)CAPT);
  const unsigned* tb = g_tbkt + (size_t)tile*CAPT;
  const float* xb0 = x + (size_t)b0*NLD;
  const float* xb1 = xb0 + NLD;
  for (unsigned k2 = lid; k2 < nT; k2 += 256) {
    unsigned e = tb[k2];
    unsigned pos = e & 511, i = e >> 9;
    atomicAdd(&s_gridf[pos],          xb0[i]);
    atomicAdd(&s_gridf[HCELLS + pos], xb1[i]);
  }
  __syncthreads();

  for (int q = lid; q < 2*HCELLS; q += 256)
    s_gridb[q] = (unsigned short)(cvtpk(s_gridf[q], 0.f) & 0xFFFFu);
  __syncthreads();

  // ---- A+P on matrix pipe, two batches interleaved ----
  {
    const int n_px = l & 15, kg = l >> 4;
    const int ce = kg * 4;
    const float4 eb = *(const float4*)&s_b1[ce];
    const float4 ea = *(const float4*)&s_bnA[ce];
    const float4 eB = *(const float4*)&s_bnB[ce];
    const int srcA = (n_px + (kg & 1)*32) * 4;
    const int srcB = srcA + 16*4;

    for (int grp = wid; grp < NGRP; grp += 4) {
      int p = grp*16 + n_px;
      unsigned rr = ((unsigned)p * 3641u) >> 16;     // p/18
      unsigned cc = (unsigned)p - rr*18u;
      int yh = ty0 - 1 + (int)rr, yw = tx0 - 1 + (int)cc;
      bool val = ((unsigned)yh < HH) & ((unsigned)yw < WW);
      const int gofs = rr*GR + cc;

      uint4 gu0 = make_uint4(0u,0u,0u,0u), gu1 = make_uint4(0u,0u,0u,0u);
      {
        const unsigned short* g0 = &s_gridb[gofs];
        const unsigned short* g1 = &s_gridb[HCELLS + gofs];
        if (kg == 0) {
          gu0.x = (unsigned)g0[0]    | ((unsigned)g0[1]      << 16);
          gu0.y = (unsigned)g0[2]    | ((unsigned)g0[GR]     << 16);
          gu0.z = (unsigned)g0[GR+1] | ((unsigned)g0[GR+2]   << 16);
          gu0.w = (unsigned)g0[2*GR] | ((unsigned)g0[2*GR+1] << 16);
          gu1.x = (unsigned)g1[0]    | ((unsigned)g1[1]      << 16);
          gu1.y = (unsigned)g1[2]    | ((unsigned)g1[GR]     << 16);
          gu1.z = (unsigned)g1[GR+1] | ((unsigned)g1[GR+2]   << 16);
          gu1.w = (unsigned)g1[2*GR] | ((unsigned)g1[2*GR+1] << 16);
        } else if (kg == 1) {
          gu0.x = (unsigned)g0[2*GR+2];
          gu1.x = (unsigned)g1[2*GR+2];
        }
      }
      bf16x8 gf0 = __builtin_bit_cast(bf16x8, gu0);
      bf16x8 gf1 = __builtin_bit_cast(bf16x8, gu1);

      // conv1 x2 (independent)
      f32x4 d10 = {0.f,0.f,0.f,0.f}, d11 = {0.f,0.f,0.f,0.f};
      d10 = __builtin_amdgcn_mfma_f32_16x16x32_bf16(w1frag, gf0, d10, 0, 0, 0);
      d11 = __builtin_amdgcn_mfma_f32_16x16x32_bf16(w1frag, gf1, d11, 0, 0, 0);

      // epilog + pack x2
      unsigned u00, u01, u10, u11;
      {
        float a0 = fmaf(fmaxf(d10[0] + eb.x, 0.f), ea.x, eB.x);
        float a1 = fmaf(fmaxf(d10[1] + eb.y, 0.f), ea.y, eB.y);
        float a2 = fmaf(fmaxf(d10[2] + eb.z, 0.f), ea.z, eB.z);
        float a3 = fmaf(fmaxf(d10[3] + eb.w, 0.f), ea.w, eB.w);
        u00 = val ? cvtpk(a0, a1) : 0u;
        u01 = val ? cvtpk(a2, a3) : 0u;
        float c0 = fmaf(fmaxf(d11[0] + eb.x, 0.f), ea.x, eB.x);
        float c1 = fmaf(fmaxf(d11[1] + eb.y, 0.f), ea.y, eB.y);
        float c2 = fmaf(fmaxf(d11[2] + eb.z, 0.f), ea.z, eB.z);
        float c3 = fmaf(fmaxf(d11[3] + eb.w, 0.f), ea.w, eB.w);
        u10 = val ? cvtpk(c0, c1) : 0u;
        u11 = val ? cvtpk(c2, c3) : 0u;
      }

      // regroup x2 (8 independent bpermutes)
      unsigned A0 = __builtin_amdgcn_ds_bpermute(srcA, (int)u00);
      unsigned A1 = __builtin_amdgcn_ds_bpermute(srcA, (int)u01);
      unsigned A2 = __builtin_amdgcn_ds_bpermute(srcB, (int)u00);
      unsigned A3 = __builtin_amdgcn_ds_bpermute(srcB, (int)u01);
      unsigned C0 = __builtin_amdgcn_ds_bpermute(srcA, (int)u10);
      unsigned C1 = __builtin_amdgcn_ds_bpermute(srcA, (int)u11);
      unsigned C2 = __builtin_amdgcn_ds_bpermute(srcB, (int)u10);
      unsigned C3 = __builtin_amdgcn_ds_bpermute(srcB, (int)u11);
      if (kg >= 2) { A0=A1=A2=A3=0u; C0=C1=C2=C3=0u; }
      bf16x8 bf0 = __builtin_bit_cast(bf16x8, make_uint4(A0,A1,A2,A3));
      bf16x8 bf1 = __builtin_bit_cast(bf16x8, make_uint4(C0,C1,C2,C3));

      // proj x2 (independent)
      f32x4 d0 = {0.f,0.f,0.f,0.f}, d1 = {0.f,0.f,0.f,0.f};
      d0 = __builtin_amdgcn_mfma_f32_16x16x32_bf16(w2frag, bf0, d0, 0, 0, 0);
      d1 = __builtin_amdgcn_mfma_f32_16x16x32_bf16(w2frag, bf1, d1, 0, 0, 0);

      if (kg < 2) {
        *(uint2*)&s_projb[p*PSTRB + kg*4]        = make_uint2(cvtpk(d0[0], d0[1]), cvtpk(d0[2], d0[3]));
        *(uint2*)&s_projb[PBUF + p*PSTRB + kg*4] = make_uint2(cvtpk(d1[0], d1[1]), cvtpk(d1[2], d1[3]));
      } else if (kg == 2) {
        s_projb[p*PSTRB + 8]        = (unsigned short)(cvtpk(d0[0], d0[0]) & 0xFFFFu);
        s_projb[PBUF + p*PSTRB + 8] = (unsigned short)(cvtpk(d1[0], d1[0]) & 0xFFFFu);
      }
    }
  }
  __syncthreads();

  // ---- phase B x2 -> ytile (overlaid on s_gridf) ----
  float* s_ytile = s_gridf;
  {
    const int ty = lid >> 4, tx = lid & 15;
    float acc0 = b2g[0], acc1 = acc0;
    #pragma unroll
    for (int kh = 0; kh < 3; ++kh)
      #pragma unroll
      for (int kw = 0; kw < 3; ++kw) {
        int o = ((ty+kh)*YR + tx+kw)*PSTRB + kh*3+kw;
        acc0 += __uint_as_float((unsigned)s_projb[o] << 16);
        acc1 += __uint_as_float((unsigned)s_projb[PBUF + o] << 16);
      }
    s_ytile[lid]       = acc0;
    s_ytile[256 + lid] = acc1;
  }
  __syncthreads();

  // ---- fused gather epilogue: interior entries, both batches ----
  for (unsigned k2 = lid; k2 < nT; k2 += 256) {
    unsigned e = tb[k2];
    unsigned pos = e & 511;
    unsigned py = (pos * 3277u) >> 16;   // pos/20
    unsigned px = pos - py*20u;
    if (py >= 2 && py < 18 && px >= 2 && px < 18) {
      unsigned i = e >> 9;
      int o = (int)((py-2)*16 + (px-2));
      out[(size_t)b0*NLD + i]     = xb0[i] + s_ytile[o];
      out[(size_t)(b0+1)*NLD + i] = xb1[i] + s_ytile[256 + o];
    }
  }
}

extern "C" void kernel_launch(void* const* d_in, const int* in_sizes, int n_in,
                              void* d_out, int out_size, void* d_ws, size_t ws_size,
                              hipStream_t stream) {
  const float* x     = (const float*)d_in[0];
  const float* w1    = (const float*)d_in[1];
  const float* b1    = (const float*)d_in[2];
  const float* gamma = (const float*)d_in[3];
  const float* beta  = (const float*)d_in[4];
  const float* mmean = (const float*)d_in[5];
  const float* mvar  = (const float*)d_in[6];
  const float* w2    = (const float*)d_in[7];
  const float* b2    = (const float*)d_in[8];
  const int*   idx   = (const int*)d_in[9];
  float* out = (float*)d_out;

  unsigned* g_tcnt = (unsigned*)d_ws;                     // 1024
  unsigned* g_tbkt = g_tcnt + NTILE;                      // 1 MB
  uint4*    w2A    = (uint4*)(g_tbkt + (size_t)NTILE*CAPT);
  uint4*    w1A    = w2A + 64;

  (void)hipMemsetAsync(g_tcnt, 0, NTILE*sizeof(unsigned), stream);

  bin_k<<<dim3(64), dim3(256), 0, stream>>>(idx, w1, w2, w2A, w1A, g_tcnt, g_tbkt);

  conv_k<<<dim3((NB/2) * NTILE), dim3(256), 0, stream>>>(
      b1, gamma, beta, mmean, mvar, w1A, w2A, b2, x, g_tcnt, g_tbkt, out);
}

// Round 16
// 122.157 us; speedup vs baseline: 1.0999x; 1.0606x over previous
//
#include <hip/hip_runtime.h>
#include <hip/hip_bf16.h>

#define HH 512
#define WW 512
#define HWSZ (HH*WW)
#define NB 32
#define NLD 100000
#define NF 16
#define EPSV 1e-3f
#define TILE 16
#define GR (TILE+4)    // grid halo tile 20x20
#define HCELLS (GR*GR) // 400
#define RDW 10         // dwords per halo row in E/O copies
#define YR (TILE+2)    // y1/proj tile 18x18
#define NGRP 21        // ceil(324/16) pixel-groups
#define PSLOTS (NGRP*16)  // 336
#define PSTRB 10       // proj row stride in shorts (taps 0..8 + pad)
#define PBUF (PSLOTS*PSTRB)

#define NTILE 1024     // 32x32 tiles of 16x16
#define CAPT 256       // halo-bucket capacity (λ=152.6, σ=12.4)

typedef __attribute__((ext_vector_type(8))) short bf16x8;
typedef __attribute__((ext_vector_type(4))) float f32x4;

static __device__ __forceinline__ unsigned short f2bfu(float f) {
  __hip_bfloat16 h = __float2bfloat16(f);
  return __builtin_bit_cast(unsigned short, h);
}
static __device__ __forceinline__ unsigned cvtpk(float a, float b) {
  unsigned r;
  asm("v_cvt_pk_bf16_f32 %0, %1, %2" : "=v"(r) : "v"(a), "v"(b));
  return r;
}

// ---- bin: halo-bucket per tile (R13/R14-proven). Block 0 also builds the
// 16x16x32 A-fragments (VERIFIED layout: lane l holds m=l&15, k=(l>>4)*8+jj)
// and the 9 BN-shift constants.
// conv1 A slot map (matches the E/O row-dword gfrag): k=4*row+col, col<3 ->
// w1 tap row*3+col, col==3 -> 0 (junk cell); k12 = b1 (bias, B supplies 1.0);
// k13..31 = 0.
// proj A: m=tap, k=ch, w2' = w2*bnA (BN scale folded). ----
__global__ __launch_bounds__(256) void bin_k(const int* __restrict__ idx,
    const float* __restrict__ w1g, const float* __restrict__ b1g,
    const float* __restrict__ w2g, const float* __restrict__ gammag,
    const float* __restrict__ betag, const float* __restrict__ mmg,
    const float* __restrict__ mvg,
    uint4* __restrict__ w1A, uint4* __restrict__ w2A, float* __restrict__ g_const,
    unsigned* __restrict__ g_tcnt, unsigned* __restrict__ g_tbkt) {
  __shared__ unsigned ht[NTILE], bt[NTILE];
  const int lid = threadIdx.x;

  if (blockIdx.x == 0 && lid < 64) {
    int m = lid & 15, kg = lid >> 4;
    bf16x8 a1, a2;
    #pragma unroll
    for (int jj = 0; jj < 8; ++jj) {
      int k = kg*8 + jj;
      float v1 = 0.f;
      if (k < 12) {
        int col = k & 3, row = k >> 2;
        if (col < 3) v1 = w1g[(row*3+col)*NF + m];
      } else if (k == 12) v1 = b1g[m];
      a1[jj] = (short)f2bfu(v1);
      float v2 = 0.f;
      if (m < 9 && k < NF) {
        float bnA = gammag[k]*rsqrtf(mvg[k] + EPSV);
        v2 = w2g[m*NF + k]*bnA;
      }
      a2[jj] = (short)f2bfu(v2);
    }
    w1A[lid] = __builtin_bit_cast(uint4, a1);
    w2A[lid] = __builtin_bit_cast(uint4, a2);
  }
  if (blockIdx.x == 0 && lid >= 64 && lid < 64+9) {
    int t = lid - 64;
    float s = 0.f;
    #pragma unroll
    for (int c = 0; c < NF; ++c) {
      float A = gammag[c]*rsqrtf(mvg[c] + EPSV);
      s += w2g[t*NF + c]*(betag[c] - mmg[c]*A);
    }
    g_const[t] = s;
  }

  for (int q = lid; q < NTILE; q += 256) ht[q] = 0;
  __syncthreads();
  for (int i = blockIdx.x*256 + lid; i < NLD; i += 64*256) {
    int cell = idx[i];
    int h = cell >> 9, w = cell & 511;
    int thA = (h-2)>>4, thB = (h+2)>>4;
    int twA = (w-2)>>4, twB = (w+2)>>4;
    #pragma unroll
    for (int ah = 0; ah < 2; ++ah) {
      int th = ah ? thB : thA;
      if (th < 0 || th > 31 || (ah && thB == thA)) continue;
      #pragma unroll
      for (int aw = 0; aw < 2; ++aw) {
        int tw = aw ? twB : twA;
        if (tw < 0 || tw > 31 || (aw && twB == twA)) continue;
        atomicAdd(&ht[th*32 + tw], 1u);
      }
    }
  }
  __syncthreads();
  for (int q = lid; q < NTILE; q += 256) {
    bt[q] = ht[q] ? atomicAdd(&g_tcnt[q], ht[q]) : 0u;
    ht[q] = 0;
  }
  __syncthreads();
  for (int i = blockIdx.x*256 + lid; i < NLD; i += 64*256) {
    int cell = idx[i];
    int h = cell >> 9, w = cell & 511;
    int thA = (h-2)>>4, thB = (h+2)>>4;
    int twA = (w-2)>>4, twB = (w+2)>>4;
    #pragma unroll
    for (int ah = 0; ah < 2; ++ah) {
      int th = ah ? thB : thA;
      if (th < 0 || th > 31 || (ah && thB == thA)) continue;
      #pragma unroll
      for (int aw = 0; aw < 2; ++aw) {
        int tw = aw ? twB : twA;
        if (tw < 0 || tw > 31 || (aw && twB == twA)) continue;
        int t = th*32 + tw;
        unsigned pt = bt[t] + atomicAdd(&ht[t], 1u);
        unsigned pos = (unsigned)(h - th*16 + 2)*20u + (unsigned)(w - tw*16 + 2);
        if (pt < CAPT) g_tbkt[(size_t)t*CAPT + pt] = ((unsigned)i << 9) | pos;
      }
    }
  }
}

// ---- conv: tile x batch-pair, verified 16x16x32 dual-MFMA (R14) with:
// E/O parity halo copies (row-dword gfrag, no scalar packing), bias in
// MFMA K-slot 12, BN folded (w2' + phase-B consts). ----
__global__ __launch_bounds__(256, 4) void conv_k(
    const uint4* __restrict__ w1Ag, const uint4* __restrict__ w2Ag,
    const float* __restrict__ g_const, const float* __restrict__ b2g,
    const float* __restrict__ x,
    const unsigned* __restrict__ g_tcnt, const unsigned* __restrict__ g_tbkt,
    float* __restrict__ out)
{
  __shared__ float s_gridf[2*HCELLS];                  // scatter acc; reused as ytile
  __shared__ unsigned s_gE[2][GR*RDW];                 // bf16-pair copies, even start
  __shared__ unsigned s_gO[2][GR*RDW];                 // odd start
  __shared__ __align__(8) unsigned short s_projb[2*PBUF];
  __shared__ float s_const[12];
  // ~19.5 KB

  const int lid = threadIdx.x;
  const int j = blockIdx.x;
  const int b0 = (j & 15) * 2;
  const int tile = j >> 4;
  const int ty0 = (tile >> 5) * TILE, tx0 = (tile & 31) * TILE;

  const int l = lid & 63;
  const int wid = lid >> 6;
  const bf16x8 w1frag = __builtin_bit_cast(bf16x8, w1Ag[l]);
  const bf16x8 w2frag = __builtin_bit_cast(bf16x8, w2Ag[l]);

  if (lid < 9) s_const[lid] = g_const[lid];
  for (int q = lid; q < 2*HCELLS; q += 256) s_gridf[q] = 0.f;
  __syncthreads();

  const unsigned nT = min(g_tcnt[tile], (unsigned)CAPT);
  const unsigned* tb = g_tbkt + (size_t)tile*CAPT;
  const float* xb0 = x + (size_t)b0*NLD;
  const float* xb1 = xb0 + NLD;
  for (unsigned k2 = lid; k2 < nT; k2 += 256) {
    unsigned e = tb[k2];
    unsigned pos = e & 511, i = e >> 9;
    atomicAdd(&s_gridf[pos],          xb0[i]);
    atomicAdd(&s_gridf[HCELLS + pos], xb1[i]);
  }
  __syncthreads();

  // quantize to bf16 pair-copies: E dword jd = cells {2jd,2jd+1}; O = {2jd+1,2jd+2}
  for (int q = lid; q < 2*GR*RDW; q += 256) {
    int bb = q >= GR*RDW;
    int rj = q - bb*GR*RDW;
    int r = rj / RDW, jd = rj - r*RDW;
    const float* f = &s_gridf[bb*HCELLS + r*GR];
    int c0 = jd*2;
    s_gE[bb][rj] = cvtpk(f[c0], f[c0+1]);
    s_gO[bb][rj] = cvtpk(f[c0+1], (c0+2 < GR) ? f[c0+2] : 0.f);
  }
  __syncthreads();

  // ---- A+P: verified 16x16x32, two batch chains ----
  {
    const int n_px = l & 15, kg = l >> 4;
    const int srcA = (n_px + (kg & 1)*32) * 4;   // bpermute byte indices (proven R12)
    const int srcB = srcA + 16*4;

    for (int grp = wid; grp < NGRP; grp += 4) {
      int p = grp*16 + n_px;
      unsigned rr = ((unsigned)p * 3641u) >> 16;     // p/18
      unsigned cc = (unsigned)p - rr*18u;
      int yh = ty0 - 1 + (int)rr, yw = tx0 - 1 + (int)cc;
      bool val = ((unsigned)yh < HH) & ((unsigned)yw < WW);
      int o = (int)rr*RDW + (int)(cc >> 1);
      const unsigned* g0 = (cc & 1) ? s_gO[0] : s_gE[0];
      const unsigned* g1 = (cc & 1) ? s_gO[1] : s_gE[1];

      // gfrag: kg0 = rows rr,rr+1 (k0-7); kg1 = row rr+2 (k8-11) + bias(k12)
      uint4 gu0 = make_uint4(0u,0u,0u,0u), gu1 = make_uint4(0u,0u,0u,0u);
      if (kg == 0) {
        gu0.x = g0[o];    gu0.y = g0[o+1];
        gu0.z = g0[o+10]; gu0.w = g0[o+11];
        gu1.x = g1[o];    gu1.y = g1[o+1];
        gu1.z = g1[o+10]; gu1.w = g1[o+11];
      } else if (kg == 1) {
        gu0.x = g0[o+20]; gu0.y = g0[o+21]; gu0.z = 0x3F80u;   // {bias 1.0, 0}
        gu1.x = g1[o+20]; gu1.y = g1[o+21]; gu1.z = 0x3F80u;
      }
      bf16x8 gf0 = __builtin_bit_cast(bf16x8, gu0);
      bf16x8 gf1 = __builtin_bit_cast(bf16x8, gu1);

      // conv1+bias x2
      f32x4 d10 = {0.f,0.f,0.f,0.f}, d11 = {0.f,0.f,0.f,0.f};
      d10 = __builtin_amdgcn_mfma_f32_16x16x32_bf16(w1frag, gf0, d10, 0, 0, 0);
      d11 = __builtin_amdgcn_mfma_f32_16x16x32_bf16(w1frag, gf1, d11, 0, 0, 0);

      // relu + pack (BN folded away); OOB y1 -> 0
      unsigned u00 = val ? cvtpk(fmaxf(d10[0],0.f), fmaxf(d10[1],0.f)) : 0u;
      unsigned u01 = val ? cvtpk(fmaxf(d10[2],0.f), fmaxf(d10[3],0.f)) : 0u;
      unsigned u10 = val ? cvtpk(fmaxf(d11[0],0.f), fmaxf(d11[1],0.f)) : 0u;
      unsigned u11 = val ? cvtpk(fmaxf(d11[2],0.f), fmaxf(d11[3],0.f)) : 0u;

      // regroup 4ch/lane -> 8ch/lane (proven R12 bpermute pattern)
      unsigned A0 = __builtin_amdgcn_ds_bpermute(srcA, (int)u00);
      unsigned A1 = __builtin_amdgcn_ds_bpermute(srcA, (int)u01);
      unsigned A2 = __builtin_amdgcn_ds_bpermute(srcB, (int)u00);
      unsigned A3 = __builtin_amdgcn_ds_bpermute(srcB, (int)u01);
      unsigned C0 = __builtin_amdgcn_ds_bpermute(srcA, (int)u10);
      unsigned C1 = __builtin_amdgcn_ds_bpermute(srcA, (int)u11);
      unsigned C2 = __builtin_amdgcn_ds_bpermute(srcB, (int)u10);
      unsigned C3 = __builtin_amdgcn_ds_bpermute(srcB, (int)u11);
      if (kg >= 2) { A0=A1=A2=A3=0u; C0=C1=C2=C3=0u; }
      bf16x8 bf0 = __builtin_bit_cast(bf16x8, make_uint4(A0,A1,A2,A3));
      bf16x8 bf1 = __builtin_bit_cast(bf16x8, make_uint4(C0,C1,C2,C3));

      // proj x2
      f32x4 d0 = {0.f,0.f,0.f,0.f}, d1 = {0.f,0.f,0.f,0.f};
      d0 = __builtin_amdgcn_mfma_f32_16x16x32_bf16(w2frag, bf0, d0, 0, 0, 0);
      d1 = __builtin_amdgcn_mfma_f32_16x16x32_bf16(w2frag, bf1, d1, 0, 0, 0);

      if (kg < 2) {
        *(uint2*)&s_projb[p*PSTRB + kg*4]        = make_uint2(cvtpk(d0[0],d0[1]), cvtpk(d0[2],d0[3]));
        *(uint2*)&s_projb[PBUF + p*PSTRB + kg*4] = make_uint2(cvtpk(d1[0],d1[1]), cvtpk(d1[2],d1[3]));
      } else if (kg == 2) {
        s_projb[p*PSTRB + 8]        = (unsigned short)(cvtpk(d0[0], d0[0]) & 0xFFFFu);
        s_projb[PBUF + p*PSTRB + 8] = (unsigned short)(cvtpk(d1[0], d1[0]) & 0xFFFFu);
      }
    }
  }
  __syncthreads();

  // ---- phase B: out = b2 + sum_{valid t} const_t + sum_t proj[t] ----
  float* s_ytile = s_gridf;
  {
    const int ty = lid >> 4, tx = lid & 15;
    bool vh[3], vw[3];
    #pragma unroll
    for (int kk = 0; kk < 3; ++kk) {
      vh[kk] = (unsigned)(ty0 + ty + kk - 1) < HH;
      vw[kk] = (unsigned)(tx0 + tx + kk - 1) < WW;
    }
    float base = b2g[0];
    float acc0 = 0.f, acc1 = 0.f;
    #pragma unroll
    for (int kh = 0; kh < 3; ++kh)
      #pragma unroll
      for (int kw = 0; kw < 3; ++kw) {
        if (vh[kh] & vw[kw]) base += s_const[kh*3+kw];
        int o = ((ty+kh)*YR + tx+kw)*PSTRB + kh*3+kw;
        acc0 += __uint_as_float((unsigned)s_projb[o] << 16);
        acc1 += __uint_as_float((unsigned)s_projb[PBUF + o] << 16);
      }
    s_ytile[lid]       = base + acc0;
    s_ytile[256 + lid] = base + acc1;
  }
  __syncthreads();

  // ---- fused gather epilogue ----
  for (unsigned k2 = lid; k2 < nT; k2 += 256) {
    unsigned e = tb[k2];
    unsigned pos = e & 511;
    unsigned py = (pos * 3277u) >> 16;   // pos/20
    unsigned px2 = pos - py*20u;
    if (py >= 2 && py < 18 && px2 >= 2 && px2 < 18) {
      unsigned i = e >> 9;
      int o = (int)((py-2)*16 + (px2-2));
      out[(size_t)b0*NLD + i]     = xb0[i] + s_ytile[o];
      out[(size_t)(b0+1)*NLD + i] = xb1[i] + s_ytile[256 + o];
    }
  }
}

extern "C" void kernel_launch(void* const* d_in, const int* in_sizes, int n_in,
                              void* d_out, int out_size, void* d_ws, size_t ws_size,
                              hipStream_t stream) {
  const float* x     = (const float*)d_in[0];
  const float* w1    = (const float*)d_in[1];
  const float* b1    = (const float*)d_in[2];
  const float* gamma = (const float*)d_in[3];
  const float* beta  = (const float*)d_in[4];
  const float* mmean = (const float*)d_in[5];
  const float* mvar  = (const float*)d_in[6];
  const float* w2    = (const float*)d_in[7];
  const float* b2    = (const float*)d_in[8];
  const int*   idx   = (const int*)d_in[9];
  float* out = (float*)d_out;

  unsigned* g_tcnt = (unsigned*)d_ws;                     // 1024
  unsigned* g_tbkt = g_tcnt + NTILE;                      // 1 MB
  uint4*    w1A    = (uint4*)(g_tbkt + (size_t)NTILE*CAPT);
  uint4*    w2A    = w1A + 64;
  float*    gconst = (float*)(w2A + 64);                  // 9 floats

  (void)hipMemsetAsync(g_tcnt, 0, NTILE*sizeof(unsigned), stream);

  bin_k<<<dim3(64), dim3(256), 0, stream>>>(idx, w1, b1, w2, gamma, beta,
                                            mmean, mvar, w1A, w2A, gconst,
                                            g_tcnt, g_tbkt);

  conv_k<<<dim3((NB/2) * NTILE), dim3(256), 0, stream>>>(
      w1A, w2A, gconst, b2, x, g_tcnt, g_tbkt, out);
}

// Round 18
// 91.179 us; speedup vs baseline: 1.4736x; 1.3398x over previous
//
#include <hip/hip_runtime.h>
#include <hip/hip_bf16.h>

#define HH 512
#define WW 512
#define HWSZ (HH*WW)
#define NB 32
#define NLD 100000
#define NF 16
#define EPSV 1e-3f
#define TILE 16
#define GR (TILE+4)    // grid halo tile 20x20
#define HCELLS (GR*GR) // 400
#define RDW 10         // dwords per halo row in E/O copies
#define YR (TILE+2)    // y1/proj tile 18x18
#define NGRP 21        // ceil(324/16) pixel-groups
#define PSLOTS (NGRP*16)  // 336
#define PSTRB 10       // proj row stride in shorts (taps 0..8 + pad)
#define PBUF (PSLOTS*PSTRB)

#define NTILE 1024     // 32x32 tiles of 16x16
#define CAPT 256       // halo-bucket capacity (λ=152.6, σ=12.4)

typedef __attribute__((ext_vector_type(4))) short bf16x4;
typedef __attribute__((ext_vector_type(4))) float f32x4;

static __device__ __forceinline__ unsigned short f2bfu(float f) {
  __hip_bfloat16 h = __float2bfloat16(f);
  return __builtin_bit_cast(unsigned short, h);
}
static __device__ __forceinline__ unsigned cvtpk(float a, float b) {
  unsigned r;
  asm("v_cvt_pk_bf16_f32 %0, %1, %2" : "=v"(r) : "v"(a), "v"(b));
  return r;
}
// K=16 bf16 MFMA (lane l: m/n=l&15, k=(l>>4)*4+jj). Guard must be inside
// __HIP_DEVICE_COMPILE__ — __has_builtin(amdgcn) is FALSE on the host pass.
static __device__ __forceinline__ f32x4 mfma16(bf16x4 a, bf16x4 b, f32x4 c) {
#if defined(__HIP_DEVICE_COMPILE__)
#if __has_builtin(__builtin_amdgcn_mfma_f32_16x16x16_bf16)
  return __builtin_amdgcn_mfma_f32_16x16x16_bf16(a, b, c, 0, 0, 0);
#else
  return __builtin_amdgcn_mfma_f32_16x16x16bf16_1k(a, b, c, 0, 0, 0);
#endif
#else
  return c;  // host stub, never executed
#endif
}

// ---- bin: halo-bucket per tile (R13/R14-proven). Block 0 also builds the
// K=16 A-fragments (lane l: m=l&15, k=(l>>4)*4+jj) and 9 BN-shift consts.
// conv1 A: k=4*row+col (rows 0..2 of the 3x3 window read as 4-cell row
// dwords; col==3 junk -> 0); k12 = b1 (bias, B supplies 1.0); k13..15 = 0.
// proj A: m=tap(<9), k=ch, w2' = w2*bnA (BN scale folded). ----
__global__ __launch_bounds__(256) void bin_k(const int* __restrict__ idx,
    const float* __restrict__ w1g, const float* __restrict__ b1g,
    const float* __restrict__ w2g, const float* __restrict__ gammag,
    const float* __restrict__ betag, const float* __restrict__ mmg,
    const float* __restrict__ mvg,
    uint2* __restrict__ w1A, uint2* __restrict__ w2A, float* __restrict__ g_const,
    unsigned* __restrict__ g_tcnt, unsigned* __restrict__ g_tbkt) {
  __shared__ unsigned ht[NTILE], bt[NTILE];
  const int lid = threadIdx.x;

  if (blockIdx.x == 0 && lid < 64) {
    int m = lid & 15, kg = lid >> 4;
    bf16x4 a1, a2;
    #pragma unroll
    for (int jj = 0; jj < 4; ++jj) {
      int k = kg*4 + jj;
      float v1 = 0.f;
      if (k < 12) {
        int col = k & 3, row = k >> 2;
        if (col < 3) v1 = w1g[(row*3+col)*NF + m];
      } else if (k == 12) v1 = b1g[m];
      a1[jj] = (short)f2bfu(v1);
      float v2 = 0.f;
      if (m < 9) {
        float bnA = gammag[k]*rsqrtf(mvg[k] + EPSV);
        v2 = w2g[m*NF + k]*bnA;
      }
      a2[jj] = (short)f2bfu(v2);
    }
    w1A[lid] = __builtin_bit_cast(uint2, a1);
    w2A[lid] = __builtin_bit_cast(uint2, a2);
  }
  if (blockIdx.x == 0 && lid >= 64 && lid < 64+9) {
    int t = lid - 64;
    float s = 0.f;
    #pragma unroll
    for (int c = 0; c < NF; ++c) {
      float A = gammag[c]*rsqrtf(mvg[c] + EPSV);
      s += w2g[t*NF + c]*(betag[c] - mmg[c]*A);
    }
    g_const[t] = s;
  }

  for (int q = lid; q < NTILE; q += 256) ht[q] = 0;
  __syncthreads();
  for (int i = blockIdx.x*256 + lid; i < NLD; i += 64*256) {
    int cell = idx[i];
    int h = cell >> 9, w = cell & 511;
    int thA = (h-2)>>4, thB = (h+2)>>4;
    int twA = (w-2)>>4, twB = (w+2)>>4;
    #pragma unroll
    for (int ah = 0; ah < 2; ++ah) {
      int th = ah ? thB : thA;
      if (th < 0 || th > 31 || (ah && thB == thA)) continue;
      #pragma unroll
      for (int aw = 0; aw < 2; ++aw) {
        int tw = aw ? twB : twA;
        if (tw < 0 || tw > 31 || (aw && twB == twA)) continue;
        atomicAdd(&ht[th*32 + tw], 1u);
      }
    }
  }
  __syncthreads();
  for (int q = lid; q < NTILE; q += 256) {
    bt[q] = ht[q] ? atomicAdd(&g_tcnt[q], ht[q]) : 0u;
    ht[q] = 0;
  }
  __syncthreads();
  for (int i = blockIdx.x*256 + lid; i < NLD; i += 64*256) {
    int cell = idx[i];
    int h = cell >> 9, w = cell & 511;
    int thA = (h-2)>>4, thB = (h+2)>>4;
    int twA = (w-2)>>4, twB = (w+2)>>4;
    #pragma unroll
    for (int ah = 0; ah < 2; ++ah) {
      int th = ah ? thB : thA;
      if (th < 0 || th > 31 || (ah && thB == thA)) continue;
      #pragma unroll
      for (int aw = 0; aw < 2; ++aw) {
        int tw = aw ? twB : twA;
        if (tw < 0 || tw > 31 || (aw && twB == twA)) continue;
        int t = th*32 + tw;
        unsigned pt = bt[t] + atomicAdd(&ht[t], 1u);
        unsigned pos = (unsigned)(h - th*16 + 2)*20u + (unsigned)(w - tw*16 + 2);
        if (pt < CAPT) g_tbkt[(size_t)t*CAPT + pt] = ((unsigned)i << 9) | pos;
      }
    }
  }
}

// ---- conv: tile x batch-pair. K=16 dual-MFMA: proj's B-fragment layout
// equals conv1's D layout -> conv1 output feeds proj DIRECTLY (no
// cross-lane regroup). All 4 k-groups carry real data. ----
__global__ __launch_bounds__(256, 4) void conv_k(
    const uint2* __restrict__ w1Ag, const uint2* __restrict__ w2Ag,
    const float* __restrict__ g_const, const float* __restrict__ b2g,
    const float* __restrict__ x,
    const unsigned* __restrict__ g_tcnt, const unsigned* __restrict__ g_tbkt,
    float* __restrict__ out)
{
  __shared__ float s_gridf[2*HCELLS];                  // scatter acc; reused as ytile
  __shared__ unsigned s_gE[2][GR*RDW];                 // bf16-pair copies, even start
  __shared__ unsigned s_gO[2][GR*RDW];                 // odd start
  __shared__ __align__(8) unsigned short s_projb[2*PBUF];
  __shared__ float s_const[12];
  // ~19.5 KB

  const int lid = threadIdx.x;
  const int j = blockIdx.x;
  const int b0 = (j & 15) * 2;
  const int tile = j >> 4;
  const int ty0 = (tile >> 5) * TILE, tx0 = (tile & 31) * TILE;

  const int l = lid & 63;
  const int wid = lid >> 6;
  const bf16x4 w1frag = __builtin_bit_cast(bf16x4, w1Ag[l]);
  const bf16x4 w2frag = __builtin_bit_cast(bf16x4, w2Ag[l]);

  if (lid < 9) s_const[lid] = g_const[lid];
  for (int q = lid; q < 2*HCELLS; q += 256) s_gridf[q] = 0.f;
  __syncthreads();

  const unsigned nT = min(g_tcnt[tile], (unsigned)CAPT);
  const unsigned* tb = g_tbkt + (size_t)tile*CAPT;
  const float* xb0 = x + (size_t)b0*NLD;
  const float* xb1 = xb0 + NLD;
  for (unsigned k2 = lid; k2 < nT; k2 += 256) {
    unsigned e = tb[k2];
    unsigned pos = e & 511, i = e >> 9;
    atomicAdd(&s_gridf[pos],          xb0[i]);
    atomicAdd(&s_gridf[HCELLS + pos], xb1[i]);
  }
  __syncthreads();

  // quantize to bf16 pair-copies: E dword jd = cells {2jd,2jd+1}; O = {2jd+1,2jd+2}
  for (int q = lid; q < 2*GR*RDW; q += 256) {
    int bb = q >= GR*RDW;
    int rj = q - bb*GR*RDW;
    int r = rj / RDW, jd = rj - r*RDW;
    const float* f = &s_gridf[bb*HCELLS + r*GR];
    int c0 = jd*2;
    s_gE[bb][rj] = cvtpk(f[c0], f[c0+1]);
    s_gO[bb][rj] = cvtpk(f[c0+1], (c0+2 < GR) ? f[c0+2] : 0.f);
  }
  __syncthreads();

  // ---- A+P: K=16 chain, no cross-lane regroup ----
  {
    const int n_px = l & 15, kg = l >> 4;

    for (int grp = wid; grp < NGRP; grp += 4) {
      int p = grp*16 + n_px;
      unsigned rr = ((unsigned)p * 3641u) >> 16;     // p/18
      unsigned cc = (unsigned)p - rr*18u;
      int yh = ty0 - 1 + (int)rr, yw = tx0 - 1 + (int)cc;
      bool val = ((unsigned)yh < HH) & ((unsigned)yw < WW);
      int o = (int)rr*RDW + (int)(cc >> 1) + kg*RDW;   // kg = window row
      const unsigned* g0 = (cc & 1) ? s_gO[0] : s_gE[0];
      const unsigned* g1 = (cc & 1) ? s_gO[1] : s_gE[1];

      // gfrag: kg0/1/2 = window rows rr..rr+2 (4 cells, col3 junk); kg3 = bias 1.0 @k12
      unsigned ga0, ga1, gb0, gb1;
      if (kg < 3) { ga0 = g0[o]; ga1 = g0[o+1]; gb0 = g1[o]; gb1 = g1[o+1]; }
      else        { ga0 = 0x00003F80u; ga1 = 0u; gb0 = 0x00003F80u; gb1 = 0u; }
      bf16x4 gf0 = __builtin_bit_cast(bf16x4, make_uint2(ga0, ga1));
      bf16x4 gf1 = __builtin_bit_cast(bf16x4, make_uint2(gb0, gb1));

      // conv1+bias x2 (K=16)
      f32x4 z = {0.f,0.f,0.f,0.f};
      f32x4 d10 = mfma16(w1frag, gf0, z);
      f32x4 d11 = mfma16(w1frag, gf1, z);

      // relu + pack; D layout == proj B layout (lane: px=l&15, ch 4kg..4kg+3)
      unsigned u0a = cvtpk(fmaxf(d10[0],0.f), fmaxf(d10[1],0.f));
      unsigned u0b = cvtpk(fmaxf(d10[2],0.f), fmaxf(d10[3],0.f));
      unsigned u1a = cvtpk(fmaxf(d11[0],0.f), fmaxf(d11[1],0.f));
      unsigned u1b = cvtpk(fmaxf(d11[2],0.f), fmaxf(d11[3],0.f));
      if (!val) { u0a = u0b = u1a = u1b = 0u; }        // OOB y1 -> 0
      bf16x4 bf0 = __builtin_bit_cast(bf16x4, make_uint2(u0a, u0b));
      bf16x4 bf1 = __builtin_bit_cast(bf16x4, make_uint2(u1a, u1b));

      // proj x2 (K=16): D rows = taps 4kg..4kg+3
      f32x4 d0 = mfma16(w2frag, bf0, z);
      f32x4 d1 = mfma16(w2frag, bf1, z);

      if (kg < 2) {
        *(uint2*)&s_projb[p*PSTRB + kg*4]        = make_uint2(cvtpk(d0[0],d0[1]), cvtpk(d0[2],d0[3]));
        *(uint2*)&s_projb[PBUF + p*PSTRB + kg*4] = make_uint2(cvtpk(d1[0],d1[1]), cvtpk(d1[2],d1[3]));
      } else if (kg == 2) {
        s_projb[p*PSTRB + 8]        = (unsigned short)(cvtpk(d0[0], d0[0]) & 0xFFFFu);  // tap 8
        s_projb[PBUF + p*PSTRB + 8] = (unsigned short)(cvtpk(d1[0], d1[0]) & 0xFFFFu);
      }
    }
  }
  __syncthreads();

  // ---- phase B: out = b2 + sum_{valid t} const_t + sum_t proj[t] ----
  float* s_ytile = s_gridf;
  {
    const int ty = lid >> 4, tx = lid & 15;
    bool vh[3], vw[3];
    #pragma unroll
    for (int kk = 0; kk < 3; ++kk) {
      vh[kk] = (unsigned)(ty0 + ty + kk - 1) < HH;
      vw[kk] = (unsigned)(tx0 + tx + kk - 1) < WW;
    }
    float base = b2g[0];
    float acc0 = 0.f, acc1 = 0.f;
    #pragma unroll
    for (int kh = 0; kh < 3; ++kh)
      #pragma unroll
      for (int kw = 0; kw < 3; ++kw) {
        if (vh[kh] & vw[kw]) base += s_const[kh*3+kw];
        int o = ((ty+kh)*YR + tx+kw)*PSTRB + kh*3+kw;
        acc0 += __uint_as_float((unsigned)s_projb[o] << 16);
        acc1 += __uint_as_float((unsigned)s_projb[PBUF + o] << 16);
      }
    s_ytile[lid]       = base + acc0;
    s_ytile[256 + lid] = base + acc1;
  }
  __syncthreads();

  // ---- fused gather epilogue ----
  for (unsigned k2 = lid; k2 < nT; k2 += 256) {
    unsigned e = tb[k2];
    unsigned pos = e & 511;
    unsigned py = (pos * 3277u) >> 16;   // pos/20
    unsigned px2 = pos - py*20u;
    if (py >= 2 && py < 18 && px2 >= 2 && px2 < 18) {
      unsigned i = e >> 9;
      int o = (int)((py-2)*16 + (px2-2));
      out[(size_t)b0*NLD + i]     = xb0[i] + s_ytile[o];
      out[(size_t)(b0+1)*NLD + i] = xb1[i] + s_ytile[256 + o];
    }
  }
}

extern "C" void kernel_launch(void* const* d_in, const int* in_sizes, int n_in,
                              void* d_out, int out_size, void* d_ws, size_t ws_size,
                              hipStream_t stream) {
  const float* x     = (const float*)d_in[0];
  const float* w1    = (const float*)d_in[1];
  const float* b1    = (const float*)d_in[2];
  const float* gamma = (const float*)d_in[3];
  const float* beta  = (const float*)d_in[4];
  const float* mmean = (const float*)d_in[5];
  const float* mvar  = (const float*)d_in[6];
  const float* w2    = (const float*)d_in[7];
  const float* b2    = (const float*)d_in[8];
  const int*   idx   = (const int*)d_in[9];
  float* out = (float*)d_out;

  unsigned* g_tcnt = (unsigned*)d_ws;                     // 1024
  unsigned* g_tbkt = g_tcnt + NTILE;                      // 1 MB
  uint2*    w1A    = (uint2*)(g_tbkt + (size_t)NTILE*CAPT);
  uint2*    w2A    = w1A + 64;
  float*    gconst = (float*)(w2A + 64);                  // 9 floats

  (void)hipMemsetAsync(g_tcnt, 0, NTILE*sizeof(unsigned), stream);

  bin_k<<<dim3(64), dim3(256), 0, stream>>>(idx, w1, b1, w2, gamma, beta,
                                            mmean, mvar, w1A, w2A, gconst,
                                            g_tcnt, g_tbkt);

  conv_k<<<dim3((NB/2) * NTILE), dim3(256), 0, stream>>>(
      w1A, w2A, gconst, b2, x, g_tcnt, g_tbkt, out);
}